// Round 1
// 501.023 us; speedup vs baseline: 1.0113x; 1.0113x over previous
//
#include <hip/hip_runtime.h>
#include <math.h>

// GraphAttention: q,v [G=2048, N=256, D=128] f32; mask [G, N] i32; W [256] f32; b [1] f32
// out [G, D] f32.  Online-softmax single pass; 4 rows per step with shared reduction
// (pairing shuffles) and shared softmax rescale: 6 cross-lane ops + 2 exps per 4 rows.

constexpr int NR  = 256;   // rows per group
constexpr int DIM = 128;   // d_q = d_v
constexpr float LALPHA  = 0.2f;
constexpr float NEG_INF = -9.0e15f;

__global__ __launch_bounds__(256) void graph_attn_kernel(
    const float* __restrict__ q,    // [G, NR, DIM]
    const float* __restrict__ v,    // [G, NR, DIM]
    const int*   __restrict__ mask, // [G, NR]
    const float* __restrict__ W,    // [2*DIM]
    const float* __restrict__ bptr, // [1]
    float*       __restrict__ out)  // [G, DIM]
{
    const int g    = blockIdx.x;
    const int t    = threadIdx.x;
    const int hw   = t >> 5;    // half-wave id 0..7; owns contiguous rows [32*hw, 32*hw+32)
    const int lane = t & 31;    // lane within half-wave; owns cols 4*lane..4*lane+3
    const int wl   = t & 63;    // lane within the physical 64-wide wave
    const int L    = t & 3;     // row-slot within the 4-lane group

    __shared__ float s_mask[NR];        // 1.0 = keep, 0.0 = masked
    __shared__ float s_m[8], s_l[8];
    __shared__ float s_o[8][DIM];

    // Prefetch mask for this group (coalesced, 1 KB)
    s_mask[t] = (mask[g * NR + t] > 0) ? 1.0f : 0.0f;
    __syncthreads();

    // Per-lane slice of the weight vector (loop-invariant)
    const float4 wq = *(const float4*)(W + lane * 4);
    const float4 wv = *(const float4*)(W + DIM + lane * 4);
    const float bias = bptr[0];

    // Base pointers: contiguous 32-row block per half-wave; 4 rows/iter at
    // immediate offsets 0/512/1024/1536 B.
    const float* qp = q + (size_t)g * NR * DIM + (size_t)hw * 32 * DIM + lane * 4;
    const float* vp = v + (size_t)g * NR * DIM + (size_t)hw * 32 * DIM + lane * 4;

    const int  gbase = wl & ~3;        // base lane of this 4-lane group (bpermute src)
    const bool odd1  = (t & 1) != 0;
    const bool odd2  = (t & 2) != 0;

    // Online softmax state (per half-wave; o distributed: 4 floats/lane)
    float m = -INFINITY;
    float l = 0.0f;
    float4 o = make_float4(0.f, 0.f, 0.f, 0.f);

#pragma unroll 2
    for (int k = 0; k < 8; ++k) {
        const float* qk = qp + k * (4 * DIM);
        const float* vk = vp + k * (4 * DIM);
        const float4 q0 = *(const float4*)(qk + 0 * DIM);
        const float4 q1 = *(const float4*)(qk + 1 * DIM);
        const float4 q2 = *(const float4*)(qk + 2 * DIM);
        const float4 q3 = *(const float4*)(qk + 3 * DIM);
        const float4 v0 = *(const float4*)(vk + 0 * DIM);
        const float4 v1 = *(const float4*)(vk + 1 * DIM);
        const float4 v2 = *(const float4*)(vk + 2 * DIM);
        const float4 v3 = *(const float4*)(vk + 3 * DIM);

        // Per-lane partial dots for 4 rows: q.Wq + v.Wv over this lane's 4+4 cols
        float pe0 = q0.x*wq.x + q0.y*wq.y + q0.z*wq.z + q0.w*wq.w
                  + v0.x*wv.x + v0.y*wv.y + v0.z*wv.z + v0.w*wv.w;
        float pe1 = q1.x*wq.x + q1.y*wq.y + q1.z*wq.z + q1.w*wq.w
                  + v1.x*wv.x + v1.y*wv.y + v1.z*wv.z + v1.w*wv.w;
        float pe2 = q2.x*wq.x + q2.y*wq.y + q2.z*wq.z + q2.w*wq.w
                  + v2.x*wv.x + v2.y*wv.y + v2.z*wv.z + v2.w*wv.w;
        float pe3 = q3.x*wq.x + q3.y*wq.y + q3.z*wq.z + q3.w*wq.w
                  + v3.x*wv.x + v3.y*wv.y + v3.z*wv.z + v3.w*wv.w;

        // Pairing reduction: 4 values -> 1 value/lane in 3 shuffles,
        // then 3-step butterfly. Lane ends holding full energy of row (t&3).
        float sA = (odd1 ? pe1 : pe0) + __shfl_xor(odd1 ? pe0 : pe1, 1);
        float sB = (odd1 ? pe3 : pe2) + __shfl_xor(odd1 ? pe2 : pe3, 1);
        float s  = (odd2 ? sB  : sA ) + __shfl_xor(odd2 ? sA  : sB , 2);
        s += __shfl_xor(s, 4);
        s += __shfl_xor(s, 8);
        s += __shfl_xor(s, 16);

        float e = s + bias;
        e = fmaxf(e, LALPHA * e);                 // leaky_relu (exact for all signs)
        const int n = (hw << 5) + (k << 2) + L;   // this lane's row
        e = (s_mask[n] > 0.f) ? e : NEG_INF;      // mask fill (finite -> all-masked ok)

        // Max over the 4 rows (uniform across the half-wave)
        float gm = fmaxf(e, __shfl_xor(e, 1));
        gm = fmaxf(gm, __shfl_xor(gm, 2));

        // Shared online-softmax update: one rescale + 2 exps per 4 rows
        const float m_new = fmaxf(m, gm);
        const float scale = __expf(m - m_new);    // exp(-inf)=0 handles first iter
        const float p     = __expf(e - m_new);    // all-masked rows: exp(0)=1 (matches ref)

        // Gather the 4 rows' p (ordered) from the 4-lane group
        const float p0 = __shfl(p, gbase + 0);
        const float p1 = __shfl(p, gbase + 1);
        const float p2 = __shfl(p, gbase + 2);
        const float p3 = __shfl(p, gbase + 3);

        l = l * scale + ((p0 + p1) + (p2 + p3));
        o.x = o.x * scale + (p0*v0.x + p1*v1.x + p2*v2.x + p3*v3.x);
        o.y = o.y * scale + (p0*v0.y + p1*v1.y + p2*v2.y + p3*v3.y);
        o.z = o.z * scale + (p0*v0.z + p1*v1.z + p2*v2.z + p3*v3.z);
        o.w = o.w * scale + (p0*v0.w + p1*v1.w + p2*v2.w + p3*v3.w);
        m = m_new;
    }

    // Publish per-half-wave state
    if (lane == 0) { s_m[hw] = m; s_l[hw] = l; }
    *(float4*)(&s_o[hw][lane * 4]) = o;
    __syncthreads();

    // Merge 8 states; threads 0..127 each own one output dim
    if (t < DIM) {
        float M = s_m[0];
#pragma unroll
        for (int i = 1; i < 8; ++i) M = fmaxf(M, s_m[i]);
        float Ls = 0.f, O = 0.f;
#pragma unroll
        for (int i = 0; i < 8; ++i) {
            const float w = __expf(s_m[i] - M);   // all-masked half-waves handled (finite m)
            Ls += w * s_l[i];
            O += w * s_o[i][t];
        }
        out[(size_t)g * DIM + t] = O / Ls;
    }
}

extern "C" void kernel_launch(void* const* d_in, const int* in_sizes, int n_in,
                              void* d_out, int out_size, void* d_ws, size_t ws_size,
                              hipStream_t stream) {
    const float* q    = (const float*)d_in[0];
    const float* v    = (const float*)d_in[1];
    const int*   mask = (const int*)d_in[2];
    const float* W    = (const float*)d_in[3];
    const float* b    = (const float*)d_in[4];
    float* out = (float*)d_out;

    const int G = in_sizes[0] / (NR * DIM);   // 2048
    graph_attn_kernel<<<G, 256, 0, stream>>>(q, v, mask, W, b, out);
}

// Round 2
// 494.858 us; speedup vs baseline: 1.0239x; 1.0125x over previous
//
#include <hip/hip_runtime.h>
#include <math.h>

// GraphAttention: q,v [G=2048, N=256, D=128] f32; mask [G, N] i32; W [256] f32; b [1] f32
// out [G, D] f32.  Online-softmax single pass, 4 rows per step.
// Cross-lane reduction done with DPP (VALU pipe) instead of ds_swizzle: only ONE
// DS op (xor16) per iteration. Mask hoisted to registers; explicit depth-1
// register prefetch keeps 8 dwordx4 loads in flight every iteration.

constexpr int NR  = 256;   // rows per group
constexpr int DIM = 128;   // d_q = d_v
constexpr float LALPHA  = 0.2f;
constexpr float NEG_INF = -9.0e15f;

// DPP move: result lane i = src lane per CTRL (within 16-lane row / quad).
// bound_ctrl=true, full masks; all lanes active in the main loop.
template<int CTRL>
__device__ __forceinline__ float dpp_mov(float x) {
    return __int_as_float(
        __builtin_amdgcn_update_dpp(0, __float_as_int(x), CTRL, 0xF, 0xF, true));
}
// DPP ctrl encodings:
//  quad_perm(1,0,3,2) = 0xB1  -> xor1
//  quad_perm(2,3,0,1) = 0x4E  -> xor2
//  row_ror:4          = 0x124 -> +4 within 16-row (same L coset)
//  row_ror:8          = 0x128 -> +8 within 16-row
//  quad bcast lane j  = j*0x55 (0x00, 0x55, 0xAA, 0xFF)

__global__ __launch_bounds__(256) void graph_attn_kernel(
    const float* __restrict__ q,    // [G, NR, DIM]
    const float* __restrict__ v,    // [G, NR, DIM]
    const int*   __restrict__ mask, // [G, NR]
    const float* __restrict__ W,    // [2*DIM]
    const float* __restrict__ bptr, // [1]
    float*       __restrict__ out)  // [G, DIM]
{
    const int g    = blockIdx.x;
    const int t    = threadIdx.x;
    const int hw   = t >> 5;    // half-wave id 0..7; owns contiguous rows [32*hw, 32*hw+32)
    const int lane = t & 31;    // lane within half-wave; owns cols 4*lane..4*lane+3
    const int L    = t & 3;     // row-slot within the 4-lane group

    __shared__ float s_mask[NR];        // 1.0 = keep, 0.0 = masked
    __shared__ float s_m[8], s_l[8];
    __shared__ float s_o[8][DIM];

    // Prefetch mask for this group (coalesced, 1 KB)
    s_mask[t] = (mask[g * NR + t] > 0) ? 1.0f : 0.0f;
    __syncthreads();

    // Per-lane slice of the weight vector (loop-invariant)
    const float4 wq = *(const float4*)(W + lane * 4);
    const float4 wv = *(const float4*)(W + DIM + lane * 4);
    const float bias = bptr[0];

    const float* qp = q + (size_t)g * NR * DIM + (size_t)hw * 32 * DIM + lane * 4;
    const float* vp = v + (size_t)g * NR * DIM + (size_t)hw * 32 * DIM + lane * 4;

    // Hoist this thread's 8 mask values out of the loop (no LDS reads in loop)
    float mrow[8];
#pragma unroll
    for (int k = 0; k < 8; ++k) mrow[k] = s_mask[(hw << 5) + (k << 2) + L];

    const bool odd1 = (t & 1) != 0;
    const bool odd2 = (t & 2) != 0;

    // Online softmax state (per half-wave; o distributed: 4 floats/lane)
    float m = -INFINITY;
    float l = 0.0f;
    float4 o = make_float4(0.f, 0.f, 0.f, 0.f);

    // Prime the register double-buffer with k=0's rows
    float4 Q[4], V[4];
#pragma unroll
    for (int r = 0; r < 4; ++r) {
        Q[r] = *(const float4*)(qp + r * DIM);
        V[r] = *(const float4*)(vp + r * DIM);
    }

#pragma unroll
    for (int k = 0; k < 8; ++k) {
        // Issue next iteration's 8 loads FIRST (hidden under this iter's compute)
        float4 Qn[4], Vn[4];
        if (k < 7) {
            const float* qk = qp + (k + 1) * (4 * DIM);
            const float* vk = vp + (k + 1) * (4 * DIM);
#pragma unroll
            for (int r = 0; r < 4; ++r) {
                Qn[r] = *(const float4*)(qk + r * DIM);
                Vn[r] = *(const float4*)(vk + r * DIM);
            }
        }

        // Per-lane partial dots for 4 rows over this lane's 4+4 cols
        float pe0 = Q[0].x*wq.x + Q[0].y*wq.y + Q[0].z*wq.z + Q[0].w*wq.w
                  + V[0].x*wv.x + V[0].y*wv.y + V[0].z*wv.z + V[0].w*wv.w;
        float pe1 = Q[1].x*wq.x + Q[1].y*wq.y + Q[1].z*wq.z + Q[1].w*wq.w
                  + V[1].x*wv.x + V[1].y*wv.y + V[1].z*wv.z + V[1].w*wv.w;
        float pe2 = Q[2].x*wq.x + Q[2].y*wq.y + Q[2].z*wq.z + Q[2].w*wq.w
                  + V[2].x*wv.x + V[2].y*wv.y + V[2].z*wv.z + V[2].w*wv.w;
        float pe3 = Q[3].x*wq.x + Q[3].y*wq.y + Q[3].z*wq.z + Q[3].w*wq.w
                  + V[3].x*wv.x + V[3].y*wv.y + V[3].z*wv.z + V[3].w*wv.w;

        // Pairing reduction, all DPP: lane ends holding full 32-lane sum for row L
        float sA = (odd1 ? pe1 : pe0) + dpp_mov<0xB1>(odd1 ? pe0 : pe1);
        float sB = (odd1 ? pe3 : pe2) + dpp_mov<0xB1>(odd1 ? pe2 : pe3);
        float s  = (odd2 ? sB  : sA ) + dpp_mov<0x4E>(odd2 ? sA  : sB );
        s += dpp_mov<0x124>(s);     // +4 coset (same row L)
        s += dpp_mov<0x128>(s);     // +8 coset -> full 16-lane row sum
        s += __shfl_xor(s, 16);     // the single DS hop: cross 16-group

        float e = s + bias;
        e = fmaxf(e, LALPHA * e);                 // leaky_relu (exact for all signs)
        e = (mrow[k] > 0.f) ? e : NEG_INF;        // mask fill (finite -> all-masked ok)

        // Max over the 4 rows: quad reduction via DPP (uniform across half-wave)
        float gm = fmaxf(e, dpp_mov<0xB1>(e));
        gm = fmaxf(gm, dpp_mov<0x4E>(gm));

        // Shared online-softmax update: one rescale + 2 exps per 4 rows
        const float m_new = fmaxf(m, gm);
        const float scale = __expf(m - m_new);    // exp(-inf)=0 handles first iter
        const float p     = __expf(e - m_new);    // all-masked rows: exp(0)=1 (matches ref)

        // Gather the 4 rows' p via quad-broadcast DPP (ordered by row slot)
        const float p0 = dpp_mov<0x00>(p);
        const float p1 = dpp_mov<0x55>(p);
        const float p2 = dpp_mov<0xAA>(p);
        const float p3 = dpp_mov<0xFF>(p);

        l = l * scale + ((p0 + p1) + (p2 + p3));
        o.x = o.x * scale + (p0*V[0].x + p1*V[1].x + p2*V[2].x + p3*V[3].x);
        o.y = o.y * scale + (p0*V[0].y + p1*V[1].y + p2*V[2].y + p3*V[3].y);
        o.z = o.z * scale + (p0*V[0].z + p1*V[1].z + p2*V[2].z + p3*V[3].z);
        o.w = o.w * scale + (p0*V[0].w + p1*V[1].w + p2*V[2].w + p3*V[3].w);
        m = m_new;

        if (k < 7) {
#pragma unroll
            for (int r = 0; r < 4; ++r) { Q[r] = Qn[r]; V[r] = Vn[r]; }
        }
    }

    // Publish per-half-wave state
    if (lane == 0) { s_m[hw] = m; s_l[hw] = l; }
    *(float4*)(&s_o[hw][lane * 4]) = o;
    __syncthreads();

    // Merge 8 states; threads 0..127 each own one output dim
    if (t < DIM) {
        float M = s_m[0];
#pragma unroll
        for (int i = 1; i < 8; ++i) M = fmaxf(M, s_m[i]);
        float Ls = 0.f, O = 0.f;
#pragma unroll
        for (int i = 0; i < 8; ++i) {
            const float w = __expf(s_m[i] - M);   // all-masked half-waves handled (finite m)
            Ls += w * s_l[i];
            O += w * s_o[i][t];
        }
        out[(size_t)g * DIM + t] = O / Ls;
    }
}

extern "C" void kernel_launch(void* const* d_in, const int* in_sizes, int n_in,
                              void* d_out, int out_size, void* d_ws, size_t ws_size,
                              hipStream_t stream) {
    const float* q    = (const float*)d_in[0];
    const float* v    = (const float*)d_in[1];
    const int*   mask = (const int*)d_in[2];
    const float* W    = (const float*)d_in[3];
    const float* b    = (const float*)d_in[4];
    float* out = (float*)d_out;

    const int G = in_sizes[0] / (NR * DIM);   // 2048
    graph_attn_kernel<<<G, 256, 0, stream>>>(q, v, mask, W, b, out);
}